// Round 7
// baseline (13777.063 us; speedup 1.0000x reference)
//
#include <hip/hip_runtime.h>
#include <hip/hip_bf16.h>

#define S_LEN 2048
#define NB    32
#define NK    512     // IN_DIM == HID == 512
#define NH    512
#define N4H   2048
#define NWG   64      // worker blocks; blocks [NWG, NBLK) are fabric heaters
#define NBLK  256
#define JPW   8       // hidden columns per WG

typedef __attribute__((ext_vector_type(8)))  short    short8;
typedef __attribute__((ext_vector_type(4)))  float    floatx4;
typedef __attribute__((ext_vector_type(16))) float    floatx16;
typedef __attribute__((ext_vector_type(4)))  unsigned uintx4;

__device__ __forceinline__ short f2bf(float f) {
  union { float f; unsigned u; } v; v.f = f;
  unsigned r = v.u + 0x7fffu + ((v.u >> 16) & 1u);
  return (short)(r >> 16);
}
__device__ __forceinline__ float sigm(float x) { return 1.f / (1.f + __expf(-x)); }
__device__ __forceinline__ float ftanh(float x) {
  float e = __expf(2.f * x);
  return 1.f - 2.f / (e + 1.f);
}

// 16 x 16B poll-loads of this lane's h slice (fp32, tagged), no wait.
#define HLOAD16                                                         \
  asm volatile(                                                         \
    "global_load_dwordx4 %0,  %[p], off sc1\n\t"                        \
    "global_load_dwordx4 %1,  %[p], off offset:16 sc1\n\t"              \
    "global_load_dwordx4 %2,  %[p], off offset:64 sc1\n\t"              \
    "global_load_dwordx4 %3,  %[p], off offset:80 sc1\n\t"              \
    "global_load_dwordx4 %4,  %[p], off offset:128 sc1\n\t"             \
    "global_load_dwordx4 %5,  %[p], off offset:144 sc1\n\t"             \
    "global_load_dwordx4 %6,  %[p], off offset:192 sc1\n\t"             \
    "global_load_dwordx4 %7,  %[p], off offset:208 sc1\n\t"             \
    "global_load_dwordx4 %8,  %[p], off offset:256 sc1\n\t"             \
    "global_load_dwordx4 %9,  %[p], off offset:272 sc1\n\t"             \
    "global_load_dwordx4 %10, %[p], off offset:320 sc1\n\t"             \
    "global_load_dwordx4 %11, %[p], off offset:336 sc1\n\t"             \
    "global_load_dwordx4 %12, %[p], off offset:384 sc1\n\t"             \
    "global_load_dwordx4 %13, %[p], off offset:400 sc1\n\t"             \
    "global_load_dwordx4 %14, %[p], off offset:448 sc1\n\t"             \
    "global_load_dwordx4 %15, %[p], off offset:464 sc1"                 \
    : "=&v"(h0), "=&v"(h1), "=&v"(h2),  "=&v"(h3),                      \
      "=&v"(h4), "=&v"(h5), "=&v"(h6),  "=&v"(h7),                      \
      "=&v"(h8), "=&v"(h9), "=&v"(h10), "=&v"(h11),                     \
      "=&v"(h12), "=&v"(h13), "=&v"(h14), "=&v"(h15)                    \
    : [p] "v"(ap) : "memory")

#define CHK(x) bad |= ((x[0]^e8)&255u)|((x[1]^e8)&255u)|((x[2]^e8)&255u)|((x[3]^e8)&255u)
#define CHKALL do { bad = 0u; \
  CHK(h0);  CHK(h1);  CHK(h2);  CHK(h3);  CHK(h4);  CHK(h5);  CHK(h6);  CHK(h7); \
  CHK(h8);  CHK(h9);  CHK(h10); CHK(h11); CHK(h12); CHK(h13); CHK(h14); CHK(h15); } while (0)

__global__ __launch_bounds__(256, 1) void plstm_persist(
    const float* __restrict__ X,  const float* __restrict__ Wx, const float* __restrict__ bx,
    const float* __restrict__ Wh, const float* __restrict__ bh, const float* __restrict__ zc,
    float* __restrict__ out, float* __restrict__ hbuf,   // 2 x 64KB fp32 h (32x512), tagged
    unsigned* __restrict__ done)
{
  const int tid  = threadIdx.x;
  const int g    = blockIdx.x;

  // ================= fabric heater blocks: FMA + LLC read stream =================
  if (g >= NWG) {
    __shared__ unsigned s_done;
    if (tid == 0) s_done = 0u;
    __syncthreads();
    const unsigned XMASK = 0x7FFFFFFu;                       // 128MB window of X
    unsigned off = (unsigned)(((g - NWG) * 256 + tid) * 2048) & XMASK;
    float a0 = 1.0f, a1 = 1.1f, a2 = 1.2f, a3 = 1.3f;
    for (;;) {
      #pragma unroll 32
      for (int i = 0; i < 256; ++i) {                        // ~2000cy shader heat
        a0 = __builtin_fmaf(a0, 1.0000001f, 1e-9f);
        a1 = __builtin_fmaf(a1, 1.0000001f, 1e-9f);
        a2 = __builtin_fmaf(a2, 1.0000001f, 1e-9f);
        a3 = __builtin_fmaf(a3, 1.0000001f, 1e-9f);
      }
      {                                                      // ~1-2 TB/s LLC stream
        const char* p0 = (const char*)X + off;
        const char* p1 = (const char*)X + ((off + 0x4000000u) & XMASK);
        uintx4 t0, t1;
        asm volatile(
          "global_load_dwordx4 %0, %2, off sc1\n\t"
          "global_load_dwordx4 %1, %3, off sc1\n\t"
          "s_waitcnt vmcnt(0)"
          : "=&v"(t0), "=&v"(t1) : "v"(p0), "v"(p1) : "memory");
        asm volatile("" :: "v"(t0), "v"(t1));
        off = (off + 196608u) & XMASK;
      }
      if (tid == 0) {
        unsigned d;
        asm volatile("global_load_dword %0, %1, off sc1\n\ts_waitcnt vmcnt(0)"
                     : "=v"(d) : "v"(done) : "memory");
        if (d) __hip_atomic_store(&s_done, 1u, __ATOMIC_RELAXED,
                                  __HIP_MEMORY_SCOPE_WORKGROUP);
      }
      if (__hip_atomic_load(&s_done, __ATOMIC_RELAXED,
                            __HIP_MEMORY_SCOPE_WORKGROUP)) break;
    }
    asm volatile("" :: "v"(a0), "v"(a1), "v"(a2), "v"(a3));
    return;
  }

  // ================= worker blocks =================
  const int wv   = tid >> 6, lane = tid & 63;
  const int colN = lane & 31, kgrp = lane >> 5;
  const int arow = colN;
  const int jbase = g * JPW;

  const int qgate = colN >> 3, jj = colN & 7;
  const int nglob = qgate * NH + jbase + jj;
  short8 wxr[8], whr[8];
  #pragma unroll
  for (int it = 0; it < 8; ++it) {
    const int k0 = wv * 128 + it * 16 + kgrp * 8;
    short8 a, b;
    #pragma unroll
    for (int e = 0; e < 8; ++e) {
      a[e] = f2bf(Wx[(size_t)(k0 + e) * N4H + nglob]);
      b[e] = f2bf(Wh[(size_t)(k0 + e) * N4H + nglob]);
    }
    wxr[it] = a; whr[it] = b;
  }

  const int m_own = tid >> 3;
  const int j_own = tid & 7;
  float bsum[4];
  #pragma unroll
  for (int q = 0; q < 4; ++q)
    bsum[q] = bx[q * NH + jbase + j_own] + bh[q * NH + jbase + j_own];
  const float zcv = zc[jbase + j_own];
  float cstate = 0.f;

  __shared__ float lds_acc[2][4][32][36];   // parity-buffered: one barrier/step

  // prologue: convert X[0], issue X[1] prefetch
  short8 xf[8];
  floatx4 xnew[16];
  {
    const floatx4* p0 = (const floatx4*)(X + arow * NK);
    #pragma unroll
    for (int it = 0; it < 8; ++it) {
      const int k0 = wv * 128 + it * 16 + kgrp * 8;
      floatx4 x0 = p0[k0 >> 2], x1 = p0[(k0 >> 2) + 1];
      short8 a;
      #pragma unroll
      for (int e = 0; e < 4; ++e) { a[e] = f2bf(x0[e]); a[4+e] = f2bf(x1[e]); }
      xf[it] = a;
    }
    const floatx4* p1 = (const floatx4*)(X + (size_t)NB * NK + arow * NK);
    #pragma unroll
    for (int it = 0; it < 8; ++it) {
      const int k0 = wv * 128 + it * 16 + kgrp * 8;
      xnew[2 * it]     = p1[k0 >> 2];
      xnew[2 * it + 1] = p1[(k0 >> 2) + 1];
    }
  }

  for (int t = 0; t < S_LEN; ++t) {
    const int par = t & 1;
    uintx4 h0, h1, h2, h3, h4, h5, h6, h7, h8, h9, h10, h11, h12, h13, h14, h15;
    const char* ap = (const char*)hbuf + (size_t)((t - 1) & 1) * 65536
                   + arow * 2048 + wv * 512 + kgrp * 32;

    if (t > 0) {
      HLOAD16;                       // h poll loads first (oldest after stores)
      // convert X[t] (loads retired long ago)
      #pragma unroll
      for (int it = 0; it < 8; ++it) {
        short8 a;
        #pragma unroll
        for (int e = 0; e < 4; ++e) {
          a[e]   = f2bf(xnew[2*it][e]);
          a[4+e] = f2bf(xnew[2*it+1][e]);
        }
        xf[it] = a;
      }
      // issue X[t+1] prefetch AFTER HLOAD16: stays in flight across the step
      if (t + 1 < S_LEN) {
        const floatx4* p = (const floatx4*)(X + (size_t)(t + 1) * NB * NK + arow * NK);
        #pragma unroll
        for (int it = 0; it < 8; ++it) {
          const int k0 = wv * 128 + it * 16 + kgrp * 8;
          xnew[2 * it]     = p[k0 >> 2];
          xnew[2 * it + 1] = p[(k0 >> 2) + 1];
        }
      }
    }

    floatx16 acc;
    #pragma unroll
    for (int r = 0; r < 16; ++r) acc[r] = 0.f;

    // input-projection MFMAs (cover h-load latency)
    #pragma unroll
    for (int it = 0; it < 8; ++it)
      acc = __builtin_amdgcn_mfma_f32_32x32x16_bf16(xf[it], wxr[it], acc, 0, 0, 0);

    if (t > 0) {
      const unsigned e8 = (((unsigned)(t - 1) >> 1) + 1u) & 255u;
      unsigned bad;
      // fast path: wait h loads only (16 X loads may still be in flight)
      asm volatile("s_waitcnt vmcnt(16)" ::: "memory");
      __builtin_amdgcn_sched_barrier(0);
      CHKALL;
      while (__any((int)(bad != 0u))) {
        HLOAD16;
        asm volatile("s_waitcnt vmcnt(0)" ::: "memory");
        __builtin_amdgcn_sched_barrier(0);
        CHKALL;
      }
      uintx4 hq[16] = { h0, h1, h2, h3, h4, h5, h6, h7,
                        h8, h9, h10, h11, h12, h13, h14, h15 };
      #pragma unroll
      for (int it = 0; it < 8; ++it) {
        short8 a;
        #pragma unroll
        for (int e = 0; e < 4; ++e) {
          a[e]   = f2bf(__uint_as_float(hq[2*it][e]));
          a[4+e] = f2bf(__uint_as_float(hq[2*it+1][e]));
        }
        acc = __builtin_amdgcn_mfma_f32_32x32x16_bf16(a, whr[it], acc, 0, 0, 0);
      }
    }

    #pragma unroll
    for (int r = 0; r < 16; ++r) {
      const int row = (r & 3) + 8 * (r >> 2) + 4 * kgrp;   // verified 32x32 C/D layout
      lds_acc[par][wv][row][colN] = acc[r];
    }
    __syncthreads();

    float pre[4];
    #pragma unroll
    for (int q = 0; q < 4; ++q) {
      const int cc = q * 8 + j_own;
      pre[q] = lds_acc[par][0][m_own][cc] + lds_acc[par][1][m_own][cc]
             + lds_acc[par][2][m_own][cc] + lds_acc[par][3][m_own][cc] + bsum[q];
    }
    const float iv = sigm(pre[0]);
    const float ov = sigm(pre[1]);
    const float fv = sigm(pre[3]);
    const float zv = ftanh(pre[2] + zcv * cstate);   // peephole on block input
    cstate = iv * zv + fv * cstate;
    const float hv = ov * ftanh(cstate);

    // publish h_t immediately: single tagged fp32 store, no ack
    if (t + 1 < S_LEN) {
      union { float f; unsigned u; } pv; pv.f = hv;
      pv.u = (pv.u & 0xffffff00u) | ((((unsigned)t >> 1) + 1u) & 255u);
      float* sp = hbuf + (size_t)par * 16384 + m_own * NH + jbase + j_own;
      asm volatile("global_store_dword %0, %1, off sc1"
                   :: "v"(sp), "v"(pv.u) : "memory");
    }

    out[((size_t)t * NB + m_own) * NH + jbase + j_own] = hv;
    if (t == S_LEN - 1) {
      out[(size_t)S_LEN * NB * NH + (size_t)m_own * NH + jbase + j_own] = hv;
      out[(size_t)S_LEN * NB * NH + (size_t)NB * NH + (size_t)m_own * NH + jbase + j_own] = cstate;
    }
  }

  // block 0 releases the heaters
  if (g == 0 && tid == 0) {
    unsigned one = 1u;
    asm volatile("global_store_dword %0, %1, off sc1" :: "v"(done), "v"(one) : "memory");
  }
}

extern "C" void kernel_launch(void* const* d_in, const int* in_sizes, int n_in,
                              void* d_out, int out_size, void* d_ws, size_t ws_size,
                              hipStream_t stream) {
  const float* X  = (const float*)d_in[0];
  const float* Wx = (const float*)d_in[1];
  const float* bx = (const float*)d_in[2];
  const float* Wh = (const float*)d_in[3];
  const float* bh = (const float*)d_in[4];
  const float* zc = (const float*)d_in[5];
  float* out  = (float*)d_out;
  float* hbuf = (float*)d_ws;                               // 2 x 64KB tagged fp32 h
  unsigned* done = (unsigned*)((char*)d_ws + 131072);       // heater release flag

  hipMemsetAsync(done, 0, 4, stream);   // done=0 each launch (graph-safe)
  hipLaunchKernelGGL(plstm_persist, dim3(NBLK), dim3(256), 0, stream,
                     X, Wx, bx, Wh, bh, zc, out, hbuf, done);
}

// Round 9
// 10529.072 us; speedup vs baseline: 1.3085x; 1.3085x over previous
//
#include <hip/hip_runtime.h>
#include <hip/hip_bf16.h>

#define S_LEN 2048
#define NB    32
#define NK    512     // IN_DIM == HID == 512
#define NH    512
#define N4H   2048
#define NWG   32
#define JPW   16      // hidden columns per WG (2 col-tiles of 32x32)

typedef __attribute__((ext_vector_type(8)))  short    short8;
typedef __attribute__((ext_vector_type(4)))  float    floatx4;
typedef __attribute__((ext_vector_type(2)))  float    floatx2;
typedef __attribute__((ext_vector_type(16))) float    floatx16;
typedef __attribute__((ext_vector_type(4)))  unsigned uintx4;

__device__ __forceinline__ unsigned f2bf(float f) {
  union { float f; unsigned u; } v; v.f = f;
  unsigned r = v.u + 0x7fffu + ((v.u >> 16) & 1u);
  return r >> 16;
}
__device__ __forceinline__ float sigm(float x) { return 1.f / (1.f + __expf(-x)); }
__device__ __forceinline__ float ftanh(float x) {
  float e = __expf(2.f * x);
  return 1.f - 2.f / (e + 1.f);
}

// h granule layout (per parity, 64KB): value = (bf16(h)<<16) | tag16, 4B each.
// granule(wvq,kgq,itq,row) = 32B (8 values, k ascending) at
//   (((wvq*2+kgq)*8+itq)*32 + row) * 32.
// Consumer lane (wv,kgrp,arow): 16 x 16B loads, lanes 0-31 contiguous 1KB.
#define HLOAD16F                                                        \
  asm volatile(                                                         \
    "global_load_dwordx4 %0,  %[p0], off sc1\n\t"                       \
    "global_load_dwordx4 %1,  %[p0], off offset:16 sc1\n\t"             \
    "global_load_dwordx4 %2,  %[p0], off offset:1024 sc1\n\t"           \
    "global_load_dwordx4 %3,  %[p0], off offset:1040 sc1\n\t"           \
    "global_load_dwordx4 %4,  %[p0], off offset:2048 sc1\n\t"           \
    "global_load_dwordx4 %5,  %[p0], off offset:2064 sc1\n\t"           \
    "global_load_dwordx4 %6,  %[p0], off offset:3072 sc1\n\t"           \
    "global_load_dwordx4 %7,  %[p0], off offset:3088 sc1\n\t"           \
    "global_load_dwordx4 %8,  %[p1], off sc1\n\t"                       \
    "global_load_dwordx4 %9,  %[p1], off offset:16 sc1\n\t"             \
    "global_load_dwordx4 %10, %[p1], off offset:1024 sc1\n\t"           \
    "global_load_dwordx4 %11, %[p1], off offset:1040 sc1\n\t"           \
    "global_load_dwordx4 %12, %[p1], off offset:2048 sc1\n\t"           \
    "global_load_dwordx4 %13, %[p1], off offset:2064 sc1\n\t"           \
    "global_load_dwordx4 %14, %[p1], off offset:3072 sc1\n\t"           \
    "global_load_dwordx4 %15, %[p1], off offset:3088 sc1"               \
    : "=&v"(h0),  "=&v"(h1),  "=&v"(h2),  "=&v"(h3),                    \
      "=&v"(h4),  "=&v"(h5),  "=&v"(h6),  "=&v"(h7),                    \
      "=&v"(h8),  "=&v"(h9),  "=&v"(h10), "=&v"(h11),                   \
      "=&v"(h12), "=&v"(h13), "=&v"(h14), "=&v"(h15)                    \
    : [p0] "v"(ap0), [p1] "v"(ap1) : "memory")

// one 16B unit == one producer store -> checking dword 0 suffices
#define CHKALL do { bad  = (h0[0]^e16) | (h1[0]^e16) | (h2[0]^e16) | (h3[0]^e16)   \
                         | (h4[0]^e16) | (h5[0]^e16) | (h6[0]^e16) | (h7[0]^e16)   \
                         | (h8[0]^e16) | (h9[0]^e16) | (h10[0]^e16)| (h11[0]^e16)  \
                         | (h12[0]^e16)| (h13[0]^e16)| (h14[0]^e16)| (h15[0]^e16); \
                    bad &= 0xffffu; } while (0)

__global__ __launch_bounds__(256, 1) void plstm_persist(
    const float* __restrict__ X,  const float* __restrict__ Wx, const float* __restrict__ bx,
    const float* __restrict__ Wh, const float* __restrict__ bh, const float* __restrict__ zc,
    float* __restrict__ out, char* __restrict__ hbuf)   // 2 x 64KB tagged-bf16 h
{
  const int tid  = threadIdx.x;
  const int g    = blockIdx.x;
  const int wv   = tid >> 6, lane = tid & 63;
  const int colN = lane & 31, kgrp = lane >> 5;
  const int arow = colN;
  const int jbase = g * JPW;

  // B-fragments (weights) in registers: 2 col-tiles x this wave's K-quarter
  short8 wxr[2][8], whr[2][8];
  #pragma unroll
  for (int ct = 0; ct < 2; ++ct) {
    const int nl = ct * 32 + colN;                        // local out-col 0..63
    const int nglob = (nl >> 4) * NH + jbase + (nl & 15); // gate*NH + hidden
    #pragma unroll
    for (int it = 0; it < 8; ++it) {
      const int k0 = wv * 128 + it * 16 + kgrp * 8;
      short8 a, b;
      #pragma unroll
      for (int e = 0; e < 8; ++e) {
        a[e] = (short)f2bf(Wx[(size_t)(k0 + e) * N4H + nglob]);
        b[e] = (short)f2bf(Wh[(size_t)(k0 + e) * N4H + nglob]);
      }
      wxr[ct][it] = a; whr[ct][it] = b;
    }
  }

  // elementwise ownership: (row m_own, hidden cols jbase+jp, jbase+jp+1)
  const int m_own = tid >> 3;       // wave wv owns rows 8wv..8wv+7
  const int jp    = (tid & 7) * 2;
  float bsA[4], bsB[4];
  #pragma unroll
  for (int q = 0; q < 4; ++q) {
    bsA[q] = bx[q*NH + jbase + jp]     + bh[q*NH + jbase + jp];
    bsB[q] = bx[q*NH + jbase + jp + 1] + bh[q*NH + jbase + jp + 1];
  }
  const float zcA = zc[jbase + jp], zcB = zc[jbase + jp + 1];
  float csA = 0.f, csB = 0.f;

  __shared__ float lds_acc[4][32][72];                 // 2 tiles of 36 cols
  __shared__ __align__(16) unsigned lds_hp[32][16];    // tagged u32, wave-local

  // producer granule bases: WG g owns (wvq=g>>3, itq=g&7, kgq=0/1)
  const int pubA = (((g >> 3) * 2 + 0) * 8 + (g & 7)) * 1024;
  const int pubB = (((g >> 3) * 2 + 1) * 8 + (g & 7)) * 1024;

  // prologue: convert X[0], issue X[1] prefetch
  short8 xf[8];
  floatx4 xnew[16];
  {
    const floatx4* p0 = (const floatx4*)(X + arow * NK);
    #pragma unroll
    for (int it = 0; it < 8; ++it) {
      const int k0 = wv * 128 + it * 16 + kgrp * 8;
      floatx4 x0 = p0[k0 >> 2], x1 = p0[(k0 >> 2) + 1];
      short8 a;
      #pragma unroll
      for (int e = 0; e < 4; ++e) { a[e] = (short)f2bf(x0[e]); a[4+e] = (short)f2bf(x1[e]); }
      xf[it] = a;
    }
    const floatx4* p1 = (const floatx4*)(X + (size_t)NB * NK + arow * NK);
    #pragma unroll
    for (int it = 0; it < 8; ++it) {
      const int k0 = wv * 128 + it * 16 + kgrp * 8;
      xnew[2 * it]     = p1[k0 >> 2];
      xnew[2 * it + 1] = p1[(k0 >> 2) + 1];
    }
  }

  for (int t = 0; t < S_LEN; ++t) {
    const int par = t & 1;
    uintx4 h0, h1, h2, h3, h4, h5, h6, h7, h8, h9, h10, h11, h12, h13, h14, h15;
    const char* ap0 = hbuf + (size_t)((t - 1) & 1) * 65536
                    + (wv * 2 + kgrp) * 8192 + arow * 32;
    const char* ap1 = ap0 + 4096;

    if (t > 0) {
      HLOAD16F;                      // h poll loads first
      // convert X[t] (loads retired last step)
      #pragma unroll
      for (int it = 0; it < 8; ++it) {
        short8 a;
        #pragma unroll
        for (int e = 0; e < 4; ++e) {
          a[e]   = (short)f2bf(xnew[2*it][e]);
          a[4+e] = (short)f2bf(xnew[2*it+1][e]);
        }
        xf[it] = a;
      }
      // issue X[t+1] prefetch AFTER h loads: stays in flight across the step
      if (t + 1 < S_LEN) {
        const floatx4* p = (const floatx4*)(X + (size_t)(t + 1) * NB * NK + arow * NK);
        #pragma unroll
        for (int it = 0; it < 8; ++it) {
          const int k0 = wv * 128 + it * 16 + kgrp * 8;
          xnew[2 * it]     = p[k0 >> 2];
          xnew[2 * it + 1] = p[(k0 >> 2) + 1];
        }
      }
    }

    floatx16 acc0, acc1;
    #pragma unroll
    for (int r = 0; r < 16; ++r) { acc0[r] = 0.f; acc1[r] = 0.f; }

    // input-projection MFMAs (cover h-load latency)
    #pragma unroll
    for (int it = 0; it < 8; ++it) {
      acc0 = __builtin_amdgcn_mfma_f32_32x32x16_bf16(xf[it], wxr[0][it], acc0, 0,0,0);
      acc1 = __builtin_amdgcn_mfma_f32_32x32x16_bf16(xf[it], wxr[1][it], acc1, 0,0,0);
    }

    if (t > 0) {
      const unsigned e16 = (((unsigned)(t - 1) >> 1) + 1u) & 0xffffu;
      unsigned bad;
      if (t + 1 < S_LEN) asm volatile("s_waitcnt vmcnt(16)" ::: "memory"); // h only; X in flight
      else               asm volatile("s_waitcnt vmcnt(0)"  ::: "memory");
      __builtin_amdgcn_sched_barrier(0);
      CHKALL;
      while (__any((int)(bad != 0u))) {
        HLOAD16F;
        asm volatile("s_waitcnt vmcnt(0)" ::: "memory");
        __builtin_amdgcn_sched_barrier(0);
        CHKALL;
      }
      // reassemble bf16 fragments: d = (lo>>16) | (hi<<16), no float math
      uintx4 hq[16] = { h0, h1, h2, h3, h4, h5, h6, h7,
                        h8, h9, h10, h11, h12, h13, h14, h15 };
      #pragma unroll
      for (int it = 0; it < 8; ++it) {
        const uintx4 lo = hq[2 * it], hi = hq[2 * it + 1];
        union { uintx4 u; short8 s; } cv;
        cv.u[0] = (lo[0] >> 16) | (lo[1] & 0xffff0000u);
        cv.u[1] = (lo[2] >> 16) | (lo[3] & 0xffff0000u);
        cv.u[2] = (hi[0] >> 16) | (hi[1] & 0xffff0000u);
        cv.u[3] = (hi[2] >> 16) | (hi[3] & 0xffff0000u);
        acc0 = __builtin_amdgcn_mfma_f32_32x32x16_bf16(cv.s, whr[0][it], acc0, 0,0,0);
        acc1 = __builtin_amdgcn_mfma_f32_32x32x16_bf16(cv.s, whr[1][it], acc1, 0,0,0);
      }
    }

    // cross-wave K-reduction
    #pragma unroll
    for (int r = 0; r < 16; ++r) {
      const int row = (r & 3) + 8 * (r >> 2) + 4 * kgrp;   // verified 32x32 C/D layout
      lds_acc[wv][row][colN]      = acc0[r];
      lds_acc[wv][row][36 + colN] = acc1[r];
    }
    __syncthreads();

    float preA[4], preB[4];
    #pragma unroll
    for (int q = 0; q < 4; ++q) {
      const int cc = (q >> 1) * 36 + (q & 1) * 16 + jp;
      preA[q] = lds_acc[0][m_own][cc]   + lds_acc[1][m_own][cc]
              + lds_acc[2][m_own][cc]   + lds_acc[3][m_own][cc]   + bsA[q];
      preB[q] = lds_acc[0][m_own][cc+1] + lds_acc[1][m_own][cc+1]
              + lds_acc[2][m_own][cc+1] + lds_acc[3][m_own][cc+1] + bsB[q];
    }
    const float iA = sigm(preA[0]), oA = sigm(preA[1]), fA = sigm(preA[3]);
    const float zA = ftanh(preA[2] + zcA * csA);           // peephole on block input
    csA = iA * zA + fA * csA;
    const float hA = oA * ftanh(csA);
    const float iB = sigm(preB[0]), oB = sigm(preB[1]), fB = sigm(preB[3]);
    const float zB = ftanh(preB[2] + zcB * csB);
    csB = iB * zB + fB * csB;
    const float hB = oB * ftanh(csB);

    // publish: tagged u32 = (bf16<<16)|tag16, wave-local gather, no barrier
    if (t + 1 < S_LEN) {
      const unsigned tg = (((unsigned)t >> 1) + 1u) & 0xffffu;
      lds_hp[m_own][jp]     = (f2bf(hA) << 16) | tg;
      lds_hp[m_own][jp + 1] = (f2bf(hB) << 16) | tg;
      __builtin_amdgcn_sched_barrier(0);
      if (lane < 32) {                      // wave wv publishes its 8 rows, both granules
        const int row_l = lane >> 2, kgq = (lane >> 1) & 1, half = lane & 1;
        const int row = wv * 8 + row_l;
        uintx4 u = *(const uintx4*)&lds_hp[row][kgq * 8 + half * 4];
        char* sp = hbuf + (size_t)par * 65536 + (kgq ? pubB : pubA)
                 + row * 32 + half * 16;
        asm volatile("global_store_dwordx4 %0, %1, off sc1"
                     :: "v"(sp), "v"(u) : "memory");
      }
    }

    // output sinks (off critical path)
    floatx2 hv2; hv2[0] = hA; hv2[1] = hB;
    *(floatx2*)&out[((size_t)t * NB + m_own) * NH + jbase + jp] = hv2;
    if (t == S_LEN - 1) {
      *(floatx2*)&out[(size_t)S_LEN * NB * NH + (size_t)m_own * NH + jbase + jp] = hv2;
      floatx2 cv2; cv2[0] = csA; cv2[1] = csB;
      *(floatx2*)&out[(size_t)S_LEN * NB * NH + (size_t)NB * NH
                      + (size_t)m_own * NH + jbase + jp] = cv2;
    }

    __syncthreads();   // WAR: lds_acc reused next step
  }
}

extern "C" void kernel_launch(void* const* d_in, const int* in_sizes, int n_in,
                              void* d_out, int out_size, void* d_ws, size_t ws_size,
                              hipStream_t stream) {
  const float* X  = (const float*)d_in[0];
  const float* Wx = (const float*)d_in[1];
  const float* bx = (const float*)d_in[2];
  const float* Wh = (const float*)d_in[3];
  const float* bh = (const float*)d_in[4];
  const float* zc = (const float*)d_in[5];
  float* out = (float*)d_out;
  char* hbuf = (char*)d_ws;   // 2 x 64KB tagged h; 16-bit tags self-validate, no init

  hipLaunchKernelGGL(plstm_persist, dim3(NWG), dim3(256), 0, stream,
                     X, Wx, bx, Wh, bh, zc, out, hbuf);
}

// Round 10
// 7327.317 us; speedup vs baseline: 1.8802x; 1.4370x over previous
//
#include <hip/hip_runtime.h>
#include <hip/hip_bf16.h>

#define S_LEN 2048
#define NB    32
#define NK    512     // IN_DIM == HID == 512
#define NH    512
#define N4H   2048
#define NWG   32
#define JPW   16      // hidden columns per WG (2 col-tiles of 32x32)

typedef __attribute__((ext_vector_type(8)))  short    short8;
typedef __attribute__((ext_vector_type(4)))  float    floatx4;
typedef __attribute__((ext_vector_type(2)))  float    floatx2;
typedef __attribute__((ext_vector_type(16))) float    floatx16;
typedef __attribute__((ext_vector_type(4)))  unsigned uintx4;
typedef __attribute__((ext_vector_type(2)))  unsigned uintx2;

__device__ __forceinline__ unsigned f2bf(float f) {
  union { float f; unsigned u; } v; v.f = f;
  unsigned r = v.u + 0x7fffu + ((v.u >> 16) & 1u);
  return r >> 16;
}
__device__ __forceinline__ float sigm(float x) { return 1.f / (1.f + __expf(-x)); }
__device__ __forceinline__ float ftanh(float x) {
  float e = __expf(2.f * x);
  return 1.f - 2.f / (e + 1.f);
}

// h granule layout (per parity, 64KB): value = (bf16(h)<<16) | tag16, 4B each.
// granule(wvq,kgq,itq) = 32 rows x 32B at (((wvq*2+kgq)*8+itq)*32)*32.
// Consumer lane (wv,kgrp,arow): 16 x 16B loads, lanes 0-31 contiguous 1KB.
#define HLOAD16F                                                        \
  asm volatile(                                                         \
    "global_load_dwordx4 %0,  %[p0], off sc1\n\t"                       \
    "global_load_dwordx4 %1,  %[p0], off offset:16 sc1\n\t"             \
    "global_load_dwordx4 %2,  %[p0], off offset:1024 sc1\n\t"           \
    "global_load_dwordx4 %3,  %[p0], off offset:1040 sc1\n\t"           \
    "global_load_dwordx4 %4,  %[p0], off offset:2048 sc1\n\t"           \
    "global_load_dwordx4 %5,  %[p0], off offset:2064 sc1\n\t"           \
    "global_load_dwordx4 %6,  %[p0], off offset:3072 sc1\n\t"           \
    "global_load_dwordx4 %7,  %[p0], off offset:3088 sc1\n\t"           \
    "global_load_dwordx4 %8,  %[p1], off sc1\n\t"                       \
    "global_load_dwordx4 %9,  %[p1], off offset:16 sc1\n\t"             \
    "global_load_dwordx4 %10, %[p1], off offset:1024 sc1\n\t"           \
    "global_load_dwordx4 %11, %[p1], off offset:1040 sc1\n\t"           \
    "global_load_dwordx4 %12, %[p1], off offset:2048 sc1\n\t"           \
    "global_load_dwordx4 %13, %[p1], off offset:2064 sc1\n\t"           \
    "global_load_dwordx4 %14, %[p1], off offset:3072 sc1\n\t"           \
    "global_load_dwordx4 %15, %[p1], off offset:3088 sc1"               \
    : "=&v"(h0),  "=&v"(h1),  "=&v"(h2),  "=&v"(h3),                    \
      "=&v"(h4),  "=&v"(h5),  "=&v"(h6),  "=&v"(h7),                    \
      "=&v"(h8),  "=&v"(h9),  "=&v"(h10), "=&v"(h11),                   \
      "=&v"(h12), "=&v"(h13), "=&v"(h14), "=&v"(h15)                    \
    : [p0] "v"(ap0), [p1] "v"(ap1) : "memory")

// one 16B unit == 2 producer 8B stores; tags occupy low 16 bits of every dword
#define CHKALL do { bad  = (h0[0]^e16) | (h0[2]^e16) | (h1[0]^e16) | (h1[2]^e16)   \
                         | (h2[0]^e16) | (h2[2]^e16) | (h3[0]^e16) | (h3[2]^e16)   \
                         | (h4[0]^e16) | (h4[2]^e16) | (h5[0]^e16) | (h5[2]^e16)   \
                         | (h6[0]^e16) | (h6[2]^e16) | (h7[0]^e16) | (h7[2]^e16)   \
                         | (h8[0]^e16) | (h8[2]^e16) | (h9[0]^e16) | (h9[2]^e16)   \
                         | (h10[0]^e16)| (h10[2]^e16)| (h11[0]^e16)| (h11[2]^e16)  \
                         | (h12[0]^e16)| (h12[2]^e16)| (h13[0]^e16)| (h13[2]^e16)  \
                         | (h14[0]^e16)| (h14[2]^e16)| (h15[0]^e16)| (h15[2]^e16); \
                    bad &= 0xffffu; } while (0)

__global__ __launch_bounds__(256, 1) void plstm_persist(
    const float* __restrict__ X,  const float* __restrict__ Wx, const float* __restrict__ bx,
    const float* __restrict__ Wh, const float* __restrict__ bh, const float* __restrict__ zc,
    float* __restrict__ out, char* __restrict__ hbuf)   // 2 x 64KB tagged-bf16 h
{
  const int tid  = threadIdx.x;
  const int g    = blockIdx.x;
  const int wv   = tid >> 6, lane = tid & 63;
  const int colN = lane & 31, kgrp = lane >> 5;
  const int arow = colN;
  const int jbase = g * JPW;

  // B-fragments (weights) in registers: 2 col-tiles x this wave's K-quarter
  short8 wxr[2][8], whr[2][8];
  #pragma unroll
  for (int ct = 0; ct < 2; ++ct) {
    const int nl = ct * 32 + colN;                        // local out-col 0..63
    const int nglob = (nl >> 4) * NH + jbase + (nl & 15); // gate*NH + hidden
    #pragma unroll
    for (int it = 0; it < 8; ++it) {
      const int k0 = wv * 128 + it * 16 + kgrp * 8;
      short8 a, b;
      #pragma unroll
      for (int e = 0; e < 8; ++e) {
        a[e] = (short)f2bf(Wx[(size_t)(k0 + e) * N4H + nglob]);
        b[e] = (short)f2bf(Wh[(size_t)(k0 + e) * N4H + nglob]);
      }
      wxr[ct][it] = a; whr[ct][it] = b;
    }
  }

  // elementwise ownership: (row m_own, hidden cols jbase+jp, jbase+jp+1)
  const int m_own = tid >> 3;
  const int jp    = (tid & 7) * 2;
  float bsA[4], bsB[4];
  #pragma unroll
  for (int q = 0; q < 4; ++q) {
    bsA[q] = bx[q*NH + jbase + jp]     + bh[q*NH + jbase + jp];
    bsB[q] = bx[q*NH + jbase + jp + 1] + bh[q*NH + jbase + jp + 1];
  }
  const float zcA = zc[jbase + jp], zcB = zc[jbase + jp + 1];
  float csA = 0.f, csB = 0.f;

  __shared__ float lds_acc[4][32][72];                 // 2 tiles of 36 cols

  // direct-publish slot: this thread's 2 values inside granule layout
  // wv_t=g>>3, it_t=g&7, kg_t=jp>=8, e=jp&7
  char* const pub = hbuf
      + (size_t)((((g >> 3) * 2 + ((jp >> 3) & 1)) * 8 + (g & 7)) * 1024
                 + m_own * 32 + (jp & 7) * 4);

  // prologue: convert X[0], issue X[1] prefetch
  short8 xf[8];
  floatx4 xnew[16];
  {
    const floatx4* p0 = (const floatx4*)(X + arow * NK);
    #pragma unroll
    for (int it = 0; it < 8; ++it) {
      const int k0 = wv * 128 + it * 16 + kgrp * 8;
      floatx4 x0 = p0[k0 >> 2], x1 = p0[(k0 >> 2) + 1];
      short8 a;
      #pragma unroll
      for (int e = 0; e < 4; ++e) { a[e] = (short)f2bf(x0[e]); a[4+e] = (short)f2bf(x1[e]); }
      xf[it] = a;
    }
    const floatx4* p1 = (const floatx4*)(X + (size_t)NB * NK + arow * NK);
    #pragma unroll
    for (int it = 0; it < 8; ++it) {
      const int k0 = wv * 128 + it * 16 + kgrp * 8;
      xnew[2 * it]     = p1[k0 >> 2];
      xnew[2 * it + 1] = p1[(k0 >> 2) + 1];
    }
  }

  for (int t = 0; t < S_LEN; ++t) {
    uintx4 h0, h1, h2, h3, h4, h5, h6, h7, h8, h9, h10, h11, h12, h13, h14, h15;
    const char* ap0 = hbuf + (size_t)((t - 1) & 1) * 65536
                    + (wv * 2 + kgrp) * 8192 + arow * 32;
    const char* ap1 = ap0 + 4096;

    if (t > 0) {
      HLOAD16F;                      // h poll loads first (only VMEM outstanding)
      // convert X[t] (loads issued last step; compiler waits the right vmcnt)
      #pragma unroll
      for (int it = 0; it < 8; ++it) {
        short8 a;
        #pragma unroll
        for (int e = 0; e < 4; ++e) {
          a[e]   = (short)f2bf(xnew[2*it][e]);
          a[4+e] = (short)f2bf(xnew[2*it+1][e]);
        }
        xf[it] = a;
      }
    }

    floatx16 acc0, acc1;
    #pragma unroll
    for (int r = 0; r < 16; ++r) { acc0[r] = 0.f; acc1[r] = 0.f; }

    // input-projection MFMAs (cover h-load latency)
    #pragma unroll
    for (int it = 0; it < 8; ++it) {
      acc0 = __builtin_amdgcn_mfma_f32_32x32x16_bf16(xf[it], wxr[0][it], acc0, 0,0,0);
      acc1 = __builtin_amdgcn_mfma_f32_32x32x16_bf16(xf[it], wxr[1][it], acc1, 0,0,0);
    }

    if (t > 0) {
      const unsigned e16 = (unsigned)t & 0xffffu;   // tag = publisher step + 1
      unsigned bad;
      asm volatile("s_waitcnt vmcnt(0)" ::: "memory");
      __builtin_amdgcn_sched_barrier(0);
      CHKALL;
      if (__any((int)(bad != 0u))) {
        // one immediate fast retry (data was "almost there")
        HLOAD16F;
        asm volatile("s_waitcnt vmcnt(0)" ::: "memory");
        __builtin_amdgcn_sched_barrier(0);
        CHKALL;
        // then back off ~256cy between rounds: decongest the LLC window
        while (__any((int)(bad != 0u))) {
          __builtin_amdgcn_s_sleep(4);
          HLOAD16F;
          asm volatile("s_waitcnt vmcnt(0)" ::: "memory");
          __builtin_amdgcn_sched_barrier(0);
          CHKALL;
        }
      }
      // reassemble bf16 fragments: d = (lo>>16) | (hi<<16), no float math
      uintx4 hq[16] = { h0, h1, h2, h3, h4, h5, h6, h7,
                        h8, h9, h10, h11, h12, h13, h14, h15 };
      #pragma unroll
      for (int it = 0; it < 8; ++it) {
        const uintx4 lo = hq[2 * it], hi = hq[2 * it + 1];
        union { uintx4 u; short8 s; } cv;
        cv.u[0] = (lo[0] >> 16) | (lo[1] & 0xffff0000u);
        cv.u[1] = (lo[2] >> 16) | (lo[3] & 0xffff0000u);
        cv.u[2] = (hi[0] >> 16) | (hi[1] & 0xffff0000u);
        cv.u[3] = (hi[2] >> 16) | (hi[3] & 0xffff0000u);
        acc0 = __builtin_amdgcn_mfma_f32_32x32x16_bf16(cv.s, whr[0][it], acc0, 0,0,0);
        acc1 = __builtin_amdgcn_mfma_f32_32x32x16_bf16(cv.s, whr[1][it], acc1, 0,0,0);
      }
      // X[t+1] prefetch: issued post-poll, lands under reduce+gates+next top
      if (t + 1 < S_LEN) {
        const floatx4* p = (const floatx4*)(X + (size_t)(t + 1) * NB * NK + arow * NK);
        #pragma unroll
        for (int it = 0; it < 8; ++it) {
          const int k0 = wv * 128 + it * 16 + kgrp * 8;
          xnew[2 * it]     = p[k0 >> 2];
          xnew[2 * it + 1] = p[(k0 >> 2) + 1];
        }
      }
    }

    // cross-wave K-reduction
    #pragma unroll
    for (int r = 0; r < 16; ++r) {
      const int row = (r & 3) + 8 * (r >> 2) + 4 * kgrp;   // verified 32x32 C/D layout
      lds_acc[wv][row][colN]      = acc0[r];
      lds_acc[wv][row][36 + colN] = acc1[r];
    }
    __syncthreads();

    float preA[4], preB[4];
    #pragma unroll
    for (int q = 0; q < 4; ++q) {
      const int cc = (q >> 1) * 36 + (q & 1) * 16 + jp;
      preA[q] = lds_acc[0][m_own][cc]   + lds_acc[1][m_own][cc]
              + lds_acc[2][m_own][cc]   + lds_acc[3][m_own][cc]   + bsA[q];
      preB[q] = lds_acc[0][m_own][cc+1] + lds_acc[1][m_own][cc+1]
              + lds_acc[2][m_own][cc+1] + lds_acc[3][m_own][cc+1] + bsB[q];
    }
    const float iA = sigm(preA[0]), oA = sigm(preA[1]), fA = sigm(preA[3]);
    const float zA = ftanh(preA[2] + zcA * csA);           // peephole on block input
    csA = iA * zA + fA * csA;
    const float hA = oA * ftanh(csA);
    const float iB = sigm(preB[0]), oB = sigm(preB[1]), fB = sigm(preB[3]);
    const float zB = ftanh(preB[2] + zcB * csB);
    csB = iB * zB + fB * csB;
    const float hB = oB * ftanh(csB);

    // ---- publish: direct from registers, 8B per thread, no LDS hop ----
    if (t + 1 < S_LEN) {
      const unsigned tg = (unsigned)(t + 1) & 0xffffu;
      uintx2 u;
      u[0] = (f2bf(hA) << 16) | tg;
      u[1] = (f2bf(hB) << 16) | tg;
      char* sp = pub + (size_t)(t & 1) * 65536;
      asm volatile("global_store_dwordx2 %0, %1, off sc1"
                   :: "v"(sp), "v"(u) : "memory");
    }

    // output sinks (off critical path)
    floatx2 hv2; hv2[0] = hA; hv2[1] = hB;
    *(floatx2*)&out[((size_t)t * NB + m_own) * NH + jbase + jp] = hv2;
    if (t == S_LEN - 1) {
      *(floatx2*)&out[(size_t)S_LEN * NB * NH + (size_t)m_own * NH + jbase + jp] = hv2;
      floatx2 cv2; cv2[0] = csA; cv2[1] = csB;
      *(floatx2*)&out[(size_t)S_LEN * NB * NH + (size_t)NB * NH
                      + (size_t)m_own * NH + jbase + jp] = cv2;
    }

    __syncthreads();   // WAR: lds_acc reused next step
  }
}

extern "C" void kernel_launch(void* const* d_in, const int* in_sizes, int n_in,
                              void* d_out, int out_size, void* d_ws, size_t ws_size,
                              hipStream_t stream) {
  const float* X  = (const float*)d_in[0];
  const float* Wx = (const float*)d_in[1];
  const float* bx = (const float*)d_in[2];
  const float* Wh = (const float*)d_in[3];
  const float* bh = (const float*)d_in[4];
  const float* zc = (const float*)d_in[5];
  float* out = (float*)d_out;
  char* hbuf = (char*)d_ws;   // 2 x 64KB tagged h; 16-bit tags self-validate, no init

  hipLaunchKernelGGL(plstm_persist, dim3(NWG), dim3(256), 0, stream,
                     X, Wx, bx, Wh, bh, zc, out, hbuf);
}